// Round 1
// baseline (100.495 us; speedup 1.0000x reference)
//
#include <hip/hip_runtime.h>

#define PATCH_N 64
#define CH      4
#define PADDED  192
#define BATCH   512
#define THREADS 1024
#define PROWS   66                        // guard row 0, data rows 1..64, guard 65
#define PCOLS   76                        // guard cols + shifted 65-col data window
#define PLANE_F (PROWS * PCOLS)           // 5016 floats per channel plane
#define PLANE4  (PLANE_F / 4)             // 1254 float4 per plane
#define LDS_F   (CH * PLANE_F)            // 20064 floats = 80,256 B

__device__ __forceinline__ int   rfl_i(int x)   { return __builtin_amdgcn_readfirstlane(x); }
__device__ __forceinline__ float rfl_f(float x) { return __int_as_float(__builtin_amdgcn_readfirstlane(__float_as_int(x))); }

// H-plane gather, v2.
//   H_c(r, j) = wx0*P(r,j) + wx1*P(r,j+1), stored alignment-shifted so output
//   group x0 reads its 4 taps as ONE aligned ds_read_b128. Guard rows/cols are
//   zero so out-of-footprint taps contribute exact 0 with no masks.
// Changes vs v1 (98.2 us session best):
//   (a) guard-only LDS zeroing (~14 KB, address-disjoint from staged data) is
//       merged into the staging phase -> ONE __syncthreads instead of two and
//       ~66 KB of redundant LDS writes removed.
//   (b) row-pair compute: each thread produces out rows (y, y+1) for one
//       float4 group. out(y)=wy0*H[t]+wy1*H[t+1], out(y+1)=wy0*H[t+1]+wy1*H[t+2]
//       -> middle tap shared: 3 ds_read_b128 per channel per pair (was 4),
//       addressing amortized over 2 rows, 4.5 compute iters (was 9).
// 80,256 B LDS x 2 blocks fits 160 KiB -> 2 blocks/CU, 32 waves/CU (VGPR<=64
// via __launch_bounds__(1024,8)).
__global__ __launch_bounds__(THREADS, 8)
void reassemble_h(const float* __restrict__ patches,
                  const float* __restrict__ positions,
                  float* __restrict__ out)
{
    __shared__ float4 lds4[LDS_F / 4];
    float* __restrict__ lds = reinterpret_cast<float*>(lds4);

    const int b    = blockIdx.x;
    const int tid  = threadIdx.x;
    const int lane = tid & 63;
    const int wid  = rfl_i(tid >> 6);     // 0..15

    // ---- per-channel uniform constants (SGPR) ----
    const float* pos = positions + (size_t)b * 8;   // (1,2,C): dx[c] then dy[c]
    int   syc[CH], ac[CH], padc[CH];
    float wx0c[CH], wx1c[CH], wy0c[CH], wy1c[CH];
#pragma unroll
    for (int c = 0; c < CH; ++c) {
        const float tx  = 64.f + rfl_f(pos[c]);
        const float sxf = ceilf(tx);
        const int   sx  = rfl_i((int)sxf);            // in [2,127]
        wx1c[c] = rfl_f(sxf - tx);
        wx0c[c] = 1.f - wx1c[c];
        const float ty  = 64.f + rfl_f(pos[CH + c]);
        const float syf = ceilf(ty);
        syc[c]  = rfl_i((int)syf);
        wy1c[c] = rfl_f(syf - ty);
        wy0c[c] = 1.f - wy1c[c];
        ac[c]   = (sx - 1) >> 2;          // alignment block of left data col
        padc[c] = (sx - 1) & 3;           // column shift within 16B
    }

    // ---- guard zeroing: ONLY guard rows + guard cols (~14 KB, not 80 KB).
    // Guards are address-disjoint from the staged data region, so this runs
    // concurrently with staging below -- no barrier between them.
    if (tid < 152) {                      // full guard rows 0 and 65, 4 planes
        const int c   = tid / 38;
        const int s   = tid % 38;
        const int row = (s < 19) ? 0 : 65;
        const int g   = (s < 19) ? s : s - 19;
        lds4[c * PLANE4 + row * (PCOLS / 4) + g] = make_float4(0.f, 0.f, 0.f, 0.f);
    }
#pragma unroll
    for (int j = 0; j < 4; ++j) {         // left/right guard cols, data rows
        const int s   = j * THREADS + tid;          // 4096 slots: 4ch x 64r x 16k
        const int c   = s >> 10;
        const int r   = 1 + ((s >> 4) & 63);        // rows 1..64
        const int k   = s & 15;
        const int col = (k < 8) ? k : (60 + k);     // cols 0..7 or 68..75
        const bool z  = (k < 8) ? (col < padc[c] + 4)       // left of data
                                : (col >= padc[c] + 69);    // right of data
        if (z) lds[c * PLANE_F + r * PCOLS + col] = 0.f;
    }

    // ---- stage + horizontal pre-blend: patch row r, lane = col ----
    const float4* __restrict__ p4 =
        reinterpret_cast<const float4*>(patches) + (size_t)b * (PATCH_N * PATCH_N);
    const bool last = (lane == 63);
#pragma unroll
    for (int pass = 0; pass < 4; ++pass) {
        const int r = pass * 16 + wid;                // wave-uniform row
        const float4 v = p4[r * PATCH_N + lane];      // coalesced 1 KB/wave
#pragma unroll
        for (int c = 0; c < CH; ++c) {
            const float val = (c == 0) ? v.x : (c == 1) ? v.y : (c == 2) ? v.z : v.w;
            float vr = __shfl_down(val, 1);           // P(r, lane+1)
            vr = last ? 0.f : vr;                     // P(r,64) = 0
            const float h = fmaf(wx1c[c], vr, wx0c[c] * val);   // H(r, lane)
            float* pl = lds + c * PLANE_F + (r + 1) * PCOLS;
            pl[lane + padc[c] + 5] = h;               // data col for j=lane
            if (lane == 0) pl[padc[c] + 4] = wx1c[c] * val;     // H(r,-1)
        }
    }
    __syncthreads();                                  // the ONLY barrier

    // ---- compute: row-pair per thread, shared middle tap ----
    float4* __restrict__ o4 =
        reinterpret_cast<float4*>(out) + (size_t)b * (PADDED * PADDED / 4);

    // 96 row-pairs x 48 groups = 4608 tasks = 4*1024 + 512 (tail wave-uniform)
#pragma unroll
    for (int it = 0; it < 5; ++it) {
        if (it == 4 && tid >= 512) continue;          // static under unroll
        const int task = it * THREADS + tid;
        const int pr   = task / 48;                   // row pair (monotone in lane)
        const int xg   = task - pr * 48;              // float4 group in row
        const int y    = pr * 2;
        const int y0   = rfl_i(y);                    // wave min-y (lane0)
        float a0 = 0.f, a1 = 0.f, a2 = 0.f, a3 = 0.f; // row y
        float b0 = 0.f, b1 = 0.f, b2 = 0.f, b3 = 0.f; // row y+1

#pragma unroll
        for (int c = 0; c < CH; ++c) {
            // wave rows [y0, y0+5] vs channel out-window [sy-1, sy+63]: scalar skip
            if (y0 + 5 < syc[c] - 1 || y0 > syc[c] + 63) continue;

            const int t  = y + 1 - syc[c];            // plane row of top tap
            const int r0 = min(max(t,     0), 65);    // clamp -> guard rows
            const int r1 = min(max(t + 1, 0), 65);    // shared middle tap
            const int r2 = min(max(t + 2, 0), 65);
            const int q4 = min(max(xg - ac[c] + 1, 0), 18);  // aligned col grp
            const int base = c * PLANE4 + q4;
            const float4 W0 = lds4[base + r0 * (PCOLS / 4)]; // 3 ds_read_b128
            const float4 W1 = lds4[base + r1 * (PCOLS / 4)]; // (was 4 for 2 rows)
            const float4 W2 = lds4[base + r2 * (PCOLS / 4)];

            const float wy0 = wy0c[c], wy1 = wy1c[c];
            a0 = fmaf(wy0, W0.x, a0); a0 = fmaf(wy1, W1.x, a0);
            a1 = fmaf(wy0, W0.y, a1); a1 = fmaf(wy1, W1.y, a1);
            a2 = fmaf(wy0, W0.z, a2); a2 = fmaf(wy1, W1.z, a2);
            a3 = fmaf(wy0, W0.w, a3); a3 = fmaf(wy1, W1.w, a3);
            b0 = fmaf(wy0, W1.x, b0); b0 = fmaf(wy1, W2.x, b0);
            b1 = fmaf(wy0, W1.y, b1); b1 = fmaf(wy1, W2.y, b1);
            b2 = fmaf(wy0, W1.z, b2); b2 = fmaf(wy1, W2.z, b2);
            b3 = fmaf(wy0, W1.w, b3); b3 = fmaf(wy1, W2.w, b3);
        }

        const int idx0 = y * 48 + xg;
        o4[idx0]      = make_float4(a0, a1, a2, a3);  // contiguous per wave
        o4[idx0 + 48] = make_float4(b0, b1, b2, b3);  // next row, contiguous
    }
}

extern "C" void kernel_launch(void* const* d_in, const int* in_sizes, int n_in,
                              void* d_out, int out_size, void* d_ws, size_t ws_size,
                              hipStream_t stream) {
    const float* patches   = (const float*)d_in[0];
    const float* positions = (const float*)d_in[1];
    float* out = (float*)d_out;

    reassemble_h<<<dim3(BATCH), THREADS, 0, stream>>>(patches, positions, out);
}